// Round 10
// baseline (766.061 us; speedup 1.0000x reference)
//
#include <hip/hip_runtime.h>

typedef __bf16 bf16x8 __attribute__((ext_vector_type(8)));
typedef float floatx4 __attribute__((ext_vector_type(4)));

#define NPB 256        // nodes per bucket (power of 2)
#define NPB_SHIFT 8
#define MAXNB 1024     // max buckets supported (N <= 262144)
#define TILE 4096      // edges per binning block

static __device__ __forceinline__ float bfu_to_f(unsigned short u) {
    unsigned int x = ((unsigned int)u) << 16;
    return __builtin_bit_cast(float, x);
}
static __device__ __forceinline__ unsigned short f_to_bfu(float f) {
    unsigned int u = __builtin_bit_cast(unsigned int, f);
    unsigned int r = (u + 0x7fffu + ((u >> 16) & 1u)) >> 16;
    return (unsigned short)r;
}

// ---------------- dtype detection (parallel) ----------------
__global__ void detect_k(const unsigned short* __restrict__ bih_u,
                         const unsigned int* __restrict__ ei_u,
                         int* __restrict__ flags) {
    __shared__ int sv, sz;
    int t = threadIdx.x;  // 64
    if (t == 0) { sv = 0; sz = 0; }
    __syncthreads();
    unsigned short u = bih_u[2 * t];
    unsigned int ex = (u >> 7) & 0xFF;
    if (ex >= 64 && ex < 124) atomicAdd(&sv, 1);
    if (ei_u[2 * t + 1] == 0u) atomicAdd(&sz, 1);
    __syncthreads();
    if (t == 0) {
        flags[0] = (sv >= 48) ? 1 : 0;
        flags[1] = (sz == 64) ? 1 : 0;
    }
}

// ---------------- canonicalization ----------------

__global__ void cvt_bf16_k(const void* __restrict__ in, unsigned short* __restrict__ out,
                           int n, const int* __restrict__ flags) {
    int i = blockIdx.x * 256 + threadIdx.x;
    if (i >= n) return;
    if (flags[0]) out[i] = ((const unsigned short*)in)[i];
    else out[i] = f_to_bfu(((const float*)in)[i]);
}

__global__ void cvt_bias_k(const void* __restrict__ bih, const void* __restrict__ bhh,
                           float* __restrict__ bih_f, float* __restrict__ bhh_f,
                           const int* __restrict__ flags) {
    int i = blockIdx.x * 256 + threadIdx.x;
    if (i >= 768) return;
    const void* src = (i < 384) ? bih : bhh;
    int j = (i < 384) ? i : i - 384;
    float v = flags[0] ? bfu_to_f(((const unsigned short*)src)[j]) : ((const float*)src)[j];
    if (i < 384) bih_f[j] = v;
    else bhh_f[j] = v;
}

__global__ void out_k(const unsigned short* __restrict__ xb, void* __restrict__ out,
                      int n, const int* __restrict__ flags) {
    int i = blockIdx.x * 256 + threadIdx.x;
    if (i >= n) return;
    if (flags[0]) ((unsigned short*)out)[i] = xb[i];
    else ((float*)out)[i] = bfu_to_f(xb[i]);
}

// ---------------- hierarchical CSR build ----------------

static __device__ __forceinline__ int load_idx(const unsigned int* eiu, size_t pos, int is64) {
    return (int)eiu[is64 ? 2 * pos : pos];
}

__global__ __launch_bounds__(256) void count_k(const unsigned int* __restrict__ eiu,
                                               int* __restrict__ bucketCnt, int E,
                                               const int* __restrict__ flags) {
    __shared__ int cnt[MAXNB];
    int t = threadIdx.x;
    for (int b = t; b < MAXNB; b += 256) cnt[b] = 0;
    __syncthreads();
    int is64 = flags[1];
    int e0 = blockIdx.x * TILE;
    int e1 = min(e0 + TILE, E);
    for (int e = e0 + t; e < e1; e += 256) {
        int d = load_idx(eiu, (size_t)E + e, is64);
        atomicAdd(&cnt[d >> NPB_SHIFT], 1);
    }
    __syncthreads();
    for (int b = t; b < MAXNB; b += 256) {
        int c = cnt[b];
        if (c) atomicAdd(&bucketCnt[b], c);
    }
}

__global__ void scanB_k(const int* __restrict__ bucketCnt, int* __restrict__ bucketBase,
                        int* __restrict__ bucketCursor, int NB, int E) {
    __shared__ int sh[MAXNB];
    int t = threadIdx.x;  // 1024 threads
    int v = (t < NB) ? bucketCnt[t] : 0;
    sh[t] = v;
    __syncthreads();
    for (int off = 1; off < MAXNB; off <<= 1) {
        int u = (t >= off) ? sh[t - off] : 0;
        __syncthreads();
        sh[t] += u;
        __syncthreads();
    }
    if (t < NB) {
        int b = sh[t] - v;
        bucketBase[t] = b;
        bucketCursor[t] = b;
    }
    if (t == 0) bucketBase[NB] = E;
}

// merged 8B record {s | dloc<<20, w}; s < 2^20, dloc = d&255 (r8 win).
__global__ __launch_bounds__(256) void bin_k(const unsigned int* __restrict__ eiu,
                                             const void* __restrict__ ew,
                                             int* __restrict__ bucketCursor,
                                             uint2* __restrict__ rec8, int E,
                                             const int* __restrict__ flags) {
    __shared__ int cnt[MAXNB];
    __shared__ int basel[MAXNB];
    int t = threadIdx.x;
    for (int b = t; b < MAXNB; b += 256) cnt[b] = 0;
    __syncthreads();
    int is64 = flags[1];
    int isb = flags[0];
    int e0 = blockIdx.x * TILE;
    int e1 = min(e0 + TILE, E);
    for (int e = e0 + t; e < e1; e += 256) {
        int d = load_idx(eiu, (size_t)E + e, is64);
        atomicAdd(&cnt[d >> NPB_SHIFT], 1);
    }
    __syncthreads();
    for (int b = t; b < MAXNB; b += 256) {
        int c = cnt[b];
        basel[b] = c ? atomicAdd(&bucketCursor[b], c) : 0;
        cnt[b] = 0;
    }
    __syncthreads();
    for (int e = e0 + t; e < e1; e += 256) {
        int s = load_idx(eiu, (size_t)e, is64);
        int d = load_idx(eiu, (size_t)E + e, is64);
        float w = isb ? bfu_to_f(((const unsigned short*)ew)[e]) : ((const float*)ew)[e];
        int b = d >> NPB_SHIFT;
        int p = basel[b] + atomicAdd(&cnt[b], 1);
        rec8[p] = make_uint2((unsigned int)s | ((unsigned int)(d & 255) << 20),
                             __builtin_bit_cast(unsigned int, w));
    }
}

__global__ __launch_bounds__(256) void csr_k(const uint2* __restrict__ rec8,
                                             const int* __restrict__ bucketBase,
                                             int* __restrict__ offsets,
                                             uint2* __restrict__ rec, int N, int E) {
    __shared__ int cnt[NPB];
    __shared__ int sh[NPB];
    __shared__ int cur[NPB];
    int t = threadIdx.x;
    int b = blockIdx.x;
    int n0 = b << NPB_SHIFT;
    int nodes = min(NPB, N - n0);
    int ebase = bucketBase[b];
    int ecnt = bucketBase[b + 1] - ebase;

    cnt[t] = 0;
    __syncthreads();
    for (int i = t; i < ecnt; i += 256) {
        int d = (rec8[ebase + i].x >> 20) & 255;
        atomicAdd(&cnt[d], 1);
    }
    __syncthreads();
    int v = cnt[t];
    sh[t] = v;
    __syncthreads();
    for (int off = 1; off < NPB; off <<= 1) {
        int u = (t >= off) ? sh[t - off] : 0;
        __syncthreads();
        sh[t] += u;
        __syncthreads();
    }
    int loff = sh[t] - v;  // exclusive
    if (t < nodes) offsets[n0 + t] = ebase + loff;
    cur[t] = ebase + loff;
    if (b == 0 && t == 0) offsets[N] = E;
    __syncthreads();
    for (int i = t; i < ecnt; i += 256) {
        uint2 r = rec8[ebase + i];
        int d = (r.x >> 20) & 255;
        int p = atomicAdd(&cur[d], 1);
        rec[p] = make_uint2(r.x & 0xFFFFFu, r.y);
    }
}

// ---------------- Ut_l[j][a] = sum_k W_l[a][k] * w_ih[j][k] ----------------

static __device__ __forceinline__ float dot8_bf(uint4 wv, uint4 iv) {
    float s;
    s  = bfu_to_f((unsigned short)(wv.x)) * bfu_to_f((unsigned short)(iv.x));
    s += bfu_to_f((unsigned short)(wv.x >> 16)) * bfu_to_f((unsigned short)(iv.x >> 16));
    s += bfu_to_f((unsigned short)(wv.y)) * bfu_to_f((unsigned short)(iv.y));
    s += bfu_to_f((unsigned short)(wv.y >> 16)) * bfu_to_f((unsigned short)(iv.y >> 16));
    s += bfu_to_f((unsigned short)(wv.z)) * bfu_to_f((unsigned short)(iv.z));
    s += bfu_to_f((unsigned short)(wv.z >> 16)) * bfu_to_f((unsigned short)(iv.z >> 16));
    s += bfu_to_f((unsigned short)(wv.w)) * bfu_to_f((unsigned short)(iv.w));
    s += bfu_to_f((unsigned short)(wv.w >> 16)) * bfu_to_f((unsigned short)(iv.w >> 16));
    return s;
}

__global__ void make_ut_k(const void* __restrict__ weight, const void* __restrict__ wih,
                          unsigned short* __restrict__ Ut, const int* __restrict__ flags) {
    int idx = blockIdx.x * 256 + threadIdx.x;  // l*49152 + j*128 + a
    if (idx >= 3 * 384 * 128) return;
    int isb = flags[0];
    int a = idx & 127;
    int j = (idx >> 7) % 384;
    int l = idx / (384 * 128);
    float s = 0.f;
    if (isb) {
        const uint4* W4 = (const uint4*)((const unsigned short*)weight + (size_t)l * 16384 + a * 128);
        const uint4* I4 = (const uint4*)((const unsigned short*)wih + (size_t)j * 128);
#pragma unroll
        for (int c = 0; c < 16; c++) s += dot8_bf(W4[c], I4[c]);
    } else {
        const float4* W4 = (const float4*)((const float*)weight + (size_t)l * 16384 + a * 128);
        const float4* I4 = (const float4*)((const float*)wih + (size_t)j * 128);
#pragma unroll
        for (int c = 0; c < 32; c++) {
            float4 w = W4[c], i = I4[c];
            s += w.x * i.x + w.y * i.y + w.z * i.z + w.w * i.w;
        }
    }
    Ut[idx] = f_to_bfu(s);
}

// ---------------- pack weights into MFMA B-fragment order (cg-major) ----------------
// Bp[l][cg][j][kc][lane][8], cg = 32-channel group (0..3),
// j = s*6 + g*2 + t: s 0=Ut 1=whh, g = gate (r,z,n), t = 16-ch tile within group.
// lane covers col = (cg*2+t)*16 + (lane&15), k = kc*32 + (lane>>4)*8.
__global__ void pack_b_k(const unsigned short* __restrict__ Ut,
                         const void* __restrict__ whh,
                         unsigned short* __restrict__ Bp,
                         const int* __restrict__ flags) {
    int idx = blockIdx.x * 256 + threadIdx.x;  // 3*4*12*4*64 total
    if (idx >= 3 * 4 * 12 * 4 * 64) return;
    int lane = idx & 63;
    int kc = (idx >> 6) & 3;
    int rest = idx >> 8;           // l*48 + cg*12 + j
    int j = rest % 12;
    int cg = (rest / 12) & 3;
    int l = rest / 48;
    int s = j / 6;
    int g = (j % 6) >> 1;
    int t = j & 1;
    int col = (cg * 2 + t) * 16 + (lane & 15);   // 0..127
    int k = kc * 32 + (lane >> 4) * 8;
    int row384 = g * 128 + col;
    unsigned short tmp[8];
    const unsigned short* src;
    if (s == 0) {
        src = Ut + (size_t)l * 49152 + row384 * 128 + k;
    } else if (flags[0]) {
        src = (const unsigned short*)whh + (size_t)row384 * 128 + k;
    } else {
        const float* wf = (const float*)whh + (size_t)row384 * 128 + k;
        for (int i = 0; i < 8; i++) tmp[i] = f_to_bfu(wf[i]);
        src = tmp;
    }
    unsigned short* dst = Bp + (size_t)l * 98304 + (((size_t)(cg * 12 + j) * 4 + kc) * 64 + lane) * 8;
    for (int i = 0; i < 8; i++) dst[i] = src[i];
}

// ---------------- fused layer: agg (gather -> LDS y tile) + GRU ----------------
// v9 (resubmit — round-9 bench was an infra failure, not a kernel verdict).
// r8 post-mortem: XCD remap did NOT make gru's y reads L2-local (FETCH
// unchanged 25.8MB) — agg's 410MB streaming gather evicts y before gru runs;
// the two-kernel form pays a y HBM/L3 roundtrip + exposed L3 latency on the
// Y-phase, and gru's load-depth lever nulled 3x. Fusion: block = 128 rows x
// all 128 channels; agg gathers into a swizzled 32KB LDS y-tile (y never hits
// global); gru iterates 4 cg B-slices (48KB LDS, T14 issue-early/write-late
// restage). 80KB LDS -> 2 blocks/CU; a gathering block's BW-bound phase
// overlaps the co-resident block's MFMA/epilogue.
// Swizzle: 16B unit u_phys = u ^ (row&15); both ds_write_b128 (agg o) and
// ds_read_b128 (aY frag: u = kc*4+quad, row&15 = m16) hit the b128 floor.

__global__ __launch_bounds__(512, 4) void fused_k(const unsigned short* __restrict__ xin,
                                                  unsigned short* __restrict__ xout,
                                                  const int* __restrict__ offs,
                                                  const uint2* __restrict__ rec,
                                                  const unsigned short* __restrict__ Bp,
                                                  const float* __restrict__ bih,
                                                  const float* __restrict__ bhh, int N) {
    __shared__ unsigned short Ylds[16384];  // 32KB: 128 rows x 256B, 16B-unit swizzled
    __shared__ uint4 Blds[3072];            // 48KB: one cg slice [12][4][64] x 16B

    int tid = threadIdx.x;
    int row0 = blockIdx.x << 7;

    // issue B stage for cg=0 (completes during agg phase)
    uint4 breg[6];
    {
        const uint4* bsrc = (const uint4*)Bp;
#pragma unroll
        for (int i = 0; i < 6; i++) breg[i] = bsrc[tid + i * 512];
    }

    // ---------- agg phase: gather 128 rows into swizzled LDS tile ----------
    {
        const uint4* xp4 = (const uint4*)xin;
        int l16 = tid & 15;
        int rr = tid >> 4;  // 0..31
        auto fma_row = [&](float* acc, uint4 v, float w) {
            acc[0] += w * __builtin_bit_cast(float, v.x << 16);
            acc[1] += w * __builtin_bit_cast(float, v.x & 0xffff0000u);
            acc[2] += w * __builtin_bit_cast(float, v.y << 16);
            acc[3] += w * __builtin_bit_cast(float, v.y & 0xffff0000u);
            acc[4] += w * __builtin_bit_cast(float, v.z << 16);
            acc[5] += w * __builtin_bit_cast(float, v.z & 0xffff0000u);
            acc[6] += w * __builtin_bit_cast(float, v.w << 16);
            acc[7] += w * __builtin_bit_cast(float, v.w & 0xffff0000u);
        };
        for (int gi = 0; gi < 4; gi++) {
            int r = gi * 32 + rr;       // local row 0..127
            int node = row0 + r;
            float a0[8], a1[8];
#pragma unroll
            for (int i = 0; i < 8; i++) { a0[i] = 0.f; a1[i] = 0.f; }
            if (node < N) {
                int e = offs[node];
                int e2 = offs[node + 1];
                for (; e + 4 <= e2; e += 4) {
                    uint2 r0 = rec[e], r1 = rec[e + 1], r2 = rec[e + 2], r3 = rec[e + 3];
                    uint4 v0 = xp4[(size_t)r0.x * 16 + l16];
                    uint4 v1 = xp4[(size_t)r1.x * 16 + l16];
                    uint4 v2 = xp4[(size_t)r2.x * 16 + l16];
                    uint4 v3 = xp4[(size_t)r3.x * 16 + l16];
                    fma_row(a0, v0, __builtin_bit_cast(float, r0.y));
                    fma_row(a1, v1, __builtin_bit_cast(float, r1.y));
                    fma_row(a0, v2, __builtin_bit_cast(float, r2.y));
                    fma_row(a1, v3, __builtin_bit_cast(float, r3.y));
                }
                for (; e < e2; e++) {
                    uint2 rr2 = rec[e];
                    uint4 v = xp4[(size_t)rr2.x * 16 + l16];
                    fma_row(a0, v, __builtin_bit_cast(float, rr2.y));
                }
            }
            uint4 o;
            o.x = (unsigned int)f_to_bfu(a0[0] + a1[0]) | ((unsigned int)f_to_bfu(a0[1] + a1[1]) << 16);
            o.y = (unsigned int)f_to_bfu(a0[2] + a1[2]) | ((unsigned int)f_to_bfu(a0[3] + a1[3]) << 16);
            o.z = (unsigned int)f_to_bfu(a0[4] + a1[4]) | ((unsigned int)f_to_bfu(a0[5] + a1[5]) << 16);
            o.w = (unsigned int)f_to_bfu(a0[6] + a1[6]) | ((unsigned int)f_to_bfu(a0[7] + a1[7]) << 16);
            int u = l16 ^ (r & 15);
            *(uint4*)&Ylds[(size_t)r * 128 + u * 8] = o;
        }
    }

    // B0 -> LDS; one barrier publishes y-tile + B0
#pragma unroll
    for (int i = 0; i < 6; i++) Blds[tid + i * 512] = breg[i];
    __syncthreads();

    // ---------- GRU phase: 4 sequential channel groups ----------
    int wave = tid >> 6;
    int wc = wave & 1;       // 16-ch tile within the 32-ch group
    int wr = wave >> 1;      // 0..3: 32-row slice
    int lane = tid & 63;
    int quad = lane >> 4;
    int m16 = lane & 15;
    const unsigned short* bl = (const unsigned short*)Blds;

    int rloc[2], rA[2];
#pragma unroll
    for (int rt = 0; rt < 2; rt++) {
        rloc[rt] = wr * 32 + rt * 16 + m16;
        int rg = row0 + rloc[rt];
        rA[rt] = (rg < N) ? rg : N - 1;
    }

    for (int cg = 0; cg < 4; cg++) {
        // T14: issue next-cg B loads now; LDS write after the post-pass barrier
        if (cg < 3) {
            const uint4* bsrc = (const uint4*)(Bp + (size_t)(cg + 1) * 24576);
#pragma unroll
            for (int i = 0; i < 6; i++) breg[i] = bsrc[tid + i * 512];
        }

        // acc[rt][s]: s=0 -> r (fused gi+gh), s=1 -> z (fused), s=2 -> gi_n, s=3 -> gh_n
        floatx4 acc[2][4];
#pragma unroll
        for (int rt = 0; rt < 2; rt++)
#pragma unroll
            for (int s = 0; s < 4; s++) acc[rt][s] = (floatx4){0.f, 0.f, 0.f, 0.f};

        bf16x8 aY[2][4], aX[2][4];
#pragma unroll
        for (int rt = 0; rt < 2; rt++)
#pragma unroll
            for (int kc = 0; kc < 4; kc++) {
                int u = (kc * 4 + quad) ^ m16;
                aY[rt][kc] = *(const bf16x8*)&Ylds[(size_t)rloc[rt] * 128 + u * 8];
                aX[rt][kc] = *(const bf16x8*)(xin + (size_t)rA[rt] * 128 + kc * 32 + quad * 8);
            }

#pragma unroll
        for (int kc = 0; kc < 4; kc++) {
#pragma unroll
            for (int g = 0; g < 3; g++) {
                int jU = g * 2 + wc;
                bf16x8 b = *(const bf16x8*)(bl + ((size_t)(jU * 4 + kc) * 64 + lane) * 8);
                int s = (g == 2) ? 2 : g;
                acc[0][s] = __builtin_amdgcn_mfma_f32_16x16x32_bf16(aY[0][kc], b, acc[0][s], 0, 0, 0);
                acc[1][s] = __builtin_amdgcn_mfma_f32_16x16x32_bf16(aY[1][kc], b, acc[1][s], 0, 0, 0);
            }
        }
#pragma unroll
        for (int kc = 0; kc < 4; kc++) {
#pragma unroll
            for (int g = 0; g < 3; g++) {
                int jW = 6 + g * 2 + wc;
                bf16x8 b = *(const bf16x8*)(bl + ((size_t)(jW * 4 + kc) * 64 + lane) * 8);
                int s = (g == 2) ? 3 : g;
                acc[0][s] = __builtin_amdgcn_mfma_f32_16x16x32_bf16(aX[0][kc], b, acc[0][s], 0, 0, 0);
                acc[1][s] = __builtin_amdgcn_mfma_f32_16x16x32_bf16(aX[1][kc], b, acc[1][s], 0, 0, 0);
            }
        }

        // epilogue for this channel group
        int ch = cg * 32 + wc * 16 + m16;  // 0..127
        float b_r = bih[ch] + bhh[ch];
        float b_z = bih[128 + ch] + bhh[128 + ch];
        float bi_n = bih[256 + ch];
        float bh_n = bhh[256 + ch];
#pragma unroll
        for (int rt = 0; rt < 2; rt++) {
#pragma unroll
            for (int ri = 0; ri < 4; ri++) {
                int row = row0 + wr * 32 + rt * 16 + quad * 4 + ri;
                if (row >= N) continue;
                float sr = acc[rt][0][ri] + b_r;
                float sz = acc[rt][1][ri] + b_z;
                float gn = acc[rt][2][ri] + bi_n;
                float hn = acc[rt][3][ri] + bh_n;
                float r = __builtin_amdgcn_rcpf(1.f + __expf(-sr));
                float zg = __builtin_amdgcn_rcpf(1.f + __expf(-sz));
                float x2 = gn + r * hn;
                float n = 1.f - 2.f * __builtin_amdgcn_rcpf(1.f + __expf(2.f * x2));
                float h = bfu_to_f(xin[(size_t)row * 128 + ch]);
                float o = n + zg * (h - n);
                xout[(size_t)row * 128 + ch] = f_to_bfu(o);
            }
        }

        __syncthreads();   // all waves done reading B_cg
        if (cg < 3) {
#pragma unroll
            for (int i = 0; i < 6; i++) Blds[tid + i * 512] = breg[i];
            __syncthreads();  // B_{cg+1} visible
        }
    }
}

// ---------------- launch ----------------

extern "C" void kernel_launch(void* const* d_in, const int* in_sizes, int n_in,
                              void* d_out, int out_size, void* d_ws, size_t ws_size,
                              hipStream_t stream) {
    const int N = in_sizes[0] / 128;
    const int E = in_sizes[1];
    const int NB = (N + NPB - 1) >> NPB_SHIFT;

    const void* z = d_in[0];
    const void* ew = d_in[1];
    const void* weight = d_in[2];
    const void* wih = d_in[3];
    const void* whh = d_in[4];
    const void* bih = d_in[5];
    const void* bhh = d_in[6];
    const unsigned int* eiu = (const unsigned int*)d_in[7];

    size_t off = 0;
    char* base = (char*)d_ws;
    auto carve = [&](size_t bytes) -> void* {
        void* p = base + off;
        off = (off + bytes + 255) & ~(size_t)255;
        return p;
    };
    unsigned short* xb = (unsigned short*)carve((size_t)N * 128 * 2);
    unsigned short* xb2 = (unsigned short*)carve((size_t)N * 128 * 2);
    uint2* rec8 = (uint2*)carve((size_t)E * 8);   // binned merged records
    uint2* rec = (uint2*)carve((size_t)E * 8);    // final CSR records
    int* offsets = (int*)carve((size_t)(N + 1) * 4);
    int* bucketCnt = (int*)carve(MAXNB * 4);
    int* bucketBase = (int*)carve((MAXNB + 1) * 4);
    int* bucketCursor = (int*)carve(MAXNB * 4);
    unsigned short* Ut = (unsigned short*)carve((size_t)3 * 384 * 128 * 2);
    unsigned short* Bp = (unsigned short*)carve((size_t)3 * 48 * 4 * 64 * 8 * 2);
    float* bih_f = (float*)carve(384 * 4);
    float* bhh_f = (float*)carve(384 * 4);
    int* flags = (int*)carve(256);

    detect_k<<<1, 64, 0, stream>>>((const unsigned short*)bih, eiu, flags);

    cvt_bf16_k<<<(N * 128 + 255) / 256, 256, 0, stream>>>(z, xb, N * 128, flags);
    cvt_bias_k<<<3, 256, 0, stream>>>(bih, bhh, bih_f, bhh_f, flags);

    // hierarchical CSR build
    hipMemsetAsync(bucketCnt, 0, MAXNB * 4, stream);
    int gbin = (E + TILE - 1) / TILE;
    count_k<<<gbin, 256, 0, stream>>>(eiu, bucketCnt, E, flags);
    scanB_k<<<1, MAXNB, 0, stream>>>(bucketCnt, bucketBase, bucketCursor, NB, E);
    bin_k<<<gbin, 256, 0, stream>>>(eiu, ew, bucketCursor, rec8, E, flags);
    csr_k<<<NB, NPB, 0, stream>>>(rec8, bucketBase, offsets, rec, N, E);

    make_ut_k<<<(3 * 384 * 128 + 255) / 256, 256, 0, stream>>>(weight, wih, Ut, flags);
    pack_b_k<<<(3 * 4 * 12 * 4 * 64 + 255) / 256, 256, 0, stream>>>(Ut, whh, Bp, flags);

    const int RB = (N + 127) >> 7;

    const unsigned short* cur = xb;
    unsigned short* nxt = xb2;
    for (int l = 0; l < 3; l++) {
        fused_k<<<RB, 512, 0, stream>>>(cur, nxt, offsets, rec, Bp + (size_t)l * 98304,
                                        bih_f, bhh_f, N);
        const unsigned short* tmp = cur;
        cur = nxt;
        nxt = (unsigned short*)tmp;
    }

    out_k<<<(N * 128 + 255) / 256, 256, 0, stream>>>(cur, d_out, N * 128, flags);
}

// Round 11
// 588.635 us; speedup vs baseline: 1.3014x; 1.3014x over previous
//
#include <hip/hip_runtime.h>

typedef __bf16 bf16x8 __attribute__((ext_vector_type(8)));
typedef float floatx4 __attribute__((ext_vector_type(4)));

#define NPB 256        // nodes per bucket (power of 2)
#define NPB_SHIFT 8
#define MAXNB 1024     // max buckets supported (N <= 262144)
#define TILE 4096      // edges per binning block

static __device__ __forceinline__ float bfu_to_f(unsigned short u) {
    unsigned int x = ((unsigned int)u) << 16;
    return __builtin_bit_cast(float, x);
}
static __device__ __forceinline__ unsigned short f_to_bfu(float f) {
    unsigned int u = __builtin_bit_cast(unsigned int, f);
    unsigned int r = (u + 0x7fffu + ((u >> 16) & 1u)) >> 16;
    return (unsigned short)r;
}

// ---------------- dtype detection (parallel) ----------------
__global__ void detect_k(const unsigned short* __restrict__ bih_u,
                         const unsigned int* __restrict__ ei_u,
                         int* __restrict__ flags) {
    __shared__ int sv, sz;
    int t = threadIdx.x;  // 64
    if (t == 0) { sv = 0; sz = 0; }
    __syncthreads();
    unsigned short u = bih_u[2 * t];
    unsigned int ex = (u >> 7) & 0xFF;
    if (ex >= 64 && ex < 124) atomicAdd(&sv, 1);
    if (ei_u[2 * t + 1] == 0u) atomicAdd(&sz, 1);
    __syncthreads();
    if (t == 0) {
        flags[0] = (sv >= 48) ? 1 : 0;
        flags[1] = (sz == 64) ? 1 : 0;
    }
}

// ---------------- canonicalization ----------------

__global__ void cvt_bf16_k(const void* __restrict__ in, unsigned short* __restrict__ out,
                           int n, const int* __restrict__ flags) {
    int i = blockIdx.x * 256 + threadIdx.x;
    if (i >= n) return;
    if (flags[0]) out[i] = ((const unsigned short*)in)[i];
    else out[i] = f_to_bfu(((const float*)in)[i]);
}

__global__ void cvt_bias_k(const void* __restrict__ bih, const void* __restrict__ bhh,
                           float* __restrict__ bih_f, float* __restrict__ bhh_f,
                           const int* __restrict__ flags) {
    int i = blockIdx.x * 256 + threadIdx.x;
    if (i >= 768) return;
    const void* src = (i < 384) ? bih : bhh;
    int j = (i < 384) ? i : i - 384;
    float v = flags[0] ? bfu_to_f(((const unsigned short*)src)[j]) : ((const float*)src)[j];
    if (i < 384) bih_f[j] = v;
    else bhh_f[j] = v;
}

// ---------------- hierarchical CSR build ----------------

static __device__ __forceinline__ int load_idx(const unsigned int* eiu, size_t pos, int is64) {
    return (int)eiu[is64 ? 2 * pos : pos];
}

__global__ __launch_bounds__(256) void count_k(const unsigned int* __restrict__ eiu,
                                               int* __restrict__ bucketCnt, int E,
                                               const int* __restrict__ flags) {
    __shared__ int cnt[MAXNB];
    int t = threadIdx.x;
    for (int b = t; b < MAXNB; b += 256) cnt[b] = 0;
    __syncthreads();
    int is64 = flags[1];
    int e0 = blockIdx.x * TILE;
    int e1 = min(e0 + TILE, E);
    for (int e = e0 + t; e < e1; e += 256) {
        int d = load_idx(eiu, (size_t)E + e, is64);
        atomicAdd(&cnt[d >> NPB_SHIFT], 1);
    }
    __syncthreads();
    for (int b = t; b < MAXNB; b += 256) {
        int c = cnt[b];
        if (c) atomicAdd(&bucketCnt[b], c);
    }
}

__global__ void scanB_k(const int* __restrict__ bucketCnt, int* __restrict__ bucketBase,
                        int* __restrict__ bucketCursor, int NB, int E) {
    __shared__ int sh[MAXNB];
    int t = threadIdx.x;  // 1024 threads
    int v = (t < NB) ? bucketCnt[t] : 0;
    sh[t] = v;
    __syncthreads();
    for (int off = 1; off < MAXNB; off <<= 1) {
        int u = (t >= off) ? sh[t - off] : 0;
        __syncthreads();
        sh[t] += u;
        __syncthreads();
    }
    if (t < NB) {
        int b = sh[t] - v;
        bucketBase[t] = b;
        bucketCursor[t] = b;
    }
    if (t == 0) bucketBase[NB] = E;
}

// merged 8B record {s | dloc<<20, w}; s < 2^20, dloc = d&255 (r8 win).
__global__ __launch_bounds__(256) void bin_k(const unsigned int* __restrict__ eiu,
                                             const void* __restrict__ ew,
                                             int* __restrict__ bucketCursor,
                                             uint2* __restrict__ rec8, int E,
                                             const int* __restrict__ flags) {
    __shared__ int cnt[MAXNB];
    __shared__ int basel[MAXNB];
    int t = threadIdx.x;
    for (int b = t; b < MAXNB; b += 256) cnt[b] = 0;
    __syncthreads();
    int is64 = flags[1];
    int isb = flags[0];
    int e0 = blockIdx.x * TILE;
    int e1 = min(e0 + TILE, E);
    for (int e = e0 + t; e < e1; e += 256) {
        int d = load_idx(eiu, (size_t)E + e, is64);
        atomicAdd(&cnt[d >> NPB_SHIFT], 1);
    }
    __syncthreads();
    for (int b = t; b < MAXNB; b += 256) {
        int c = cnt[b];
        basel[b] = c ? atomicAdd(&bucketCursor[b], c) : 0;
        cnt[b] = 0;
    }
    __syncthreads();
    for (int e = e0 + t; e < e1; e += 256) {
        int s = load_idx(eiu, (size_t)e, is64);
        int d = load_idx(eiu, (size_t)E + e, is64);
        float w = isb ? bfu_to_f(((const unsigned short*)ew)[e]) : ((const float*)ew)[e];
        int b = d >> NPB_SHIFT;
        int p = basel[b] + atomicAdd(&cnt[b], 1);
        rec8[p] = make_uint2((unsigned int)s | ((unsigned int)(d & 255) << 20),
                             __builtin_bit_cast(unsigned int, w));
    }
}

__global__ __launch_bounds__(256) void csr_k(const uint2* __restrict__ rec8,
                                             const int* __restrict__ bucketBase,
                                             int* __restrict__ offsets,
                                             uint2* __restrict__ rec, int N, int E) {
    __shared__ int cnt[NPB];
    __shared__ int sh[NPB];
    __shared__ int cur[NPB];
    int t = threadIdx.x;
    int b = blockIdx.x;
    int n0 = b << NPB_SHIFT;
    int nodes = min(NPB, N - n0);
    int ebase = bucketBase[b];
    int ecnt = bucketBase[b + 1] - ebase;

    cnt[t] = 0;
    __syncthreads();
    for (int i = t; i < ecnt; i += 256) {
        int d = (rec8[ebase + i].x >> 20) & 255;
        atomicAdd(&cnt[d], 1);
    }
    __syncthreads();
    int v = cnt[t];
    sh[t] = v;
    __syncthreads();
    for (int off = 1; off < NPB; off <<= 1) {
        int u = (t >= off) ? sh[t - off] : 0;
        __syncthreads();
        sh[t] += u;
        __syncthreads();
    }
    int loff = sh[t] - v;  // exclusive
    if (t < nodes) offsets[n0 + t] = ebase + loff;
    cur[t] = ebase + loff;
    if (b == 0 && t == 0) offsets[N] = E;
    __syncthreads();
    for (int i = t; i < ecnt; i += 256) {
        uint2 r = rec8[ebase + i];
        int d = (r.x >> 20) & 255;
        int p = atomicAdd(&cur[d], 1);
        rec[p] = make_uint2(r.x & 0xFFFFFu, r.y);
    }
}

// ---------------- Ut_l[j][a] = sum_k W_l[a][k] * w_ih[j][k] ----------------

static __device__ __forceinline__ float dot8_bf(uint4 wv, uint4 iv) {
    float s;
    s  = bfu_to_f((unsigned short)(wv.x)) * bfu_to_f((unsigned short)(iv.x));
    s += bfu_to_f((unsigned short)(wv.x >> 16)) * bfu_to_f((unsigned short)(iv.x >> 16));
    s += bfu_to_f((unsigned short)(wv.y)) * bfu_to_f((unsigned short)(iv.y));
    s += bfu_to_f((unsigned short)(wv.y >> 16)) * bfu_to_f((unsigned short)(iv.y >> 16));
    s += bfu_to_f((unsigned short)(wv.z)) * bfu_to_f((unsigned short)(iv.z));
    s += bfu_to_f((unsigned short)(wv.z >> 16)) * bfu_to_f((unsigned short)(iv.z >> 16));
    s += bfu_to_f((unsigned short)(wv.w)) * bfu_to_f((unsigned short)(iv.w));
    s += bfu_to_f((unsigned short)(wv.w >> 16)) * bfu_to_f((unsigned short)(iv.w >> 16));
    return s;
}

__global__ void make_ut_k(const void* __restrict__ weight, const void* __restrict__ wih,
                          unsigned short* __restrict__ Ut, const int* __restrict__ flags) {
    int idx = blockIdx.x * 256 + threadIdx.x;  // l*49152 + j*128 + a
    if (idx >= 3 * 384 * 128) return;
    int isb = flags[0];
    int a = idx & 127;
    int j = (idx >> 7) % 384;
    int l = idx / (384 * 128);
    float s = 0.f;
    if (isb) {
        const uint4* W4 = (const uint4*)((const unsigned short*)weight + (size_t)l * 16384 + a * 128);
        const uint4* I4 = (const uint4*)((const unsigned short*)wih + (size_t)j * 128);
#pragma unroll
        for (int c = 0; c < 16; c++) s += dot8_bf(W4[c], I4[c]);
    } else {
        const float4* W4 = (const float4*)((const float*)weight + (size_t)l * 16384 + a * 128);
        const float4* I4 = (const float4*)((const float*)wih + (size_t)j * 128);
#pragma unroll
        for (int c = 0; c < 32; c++) {
            float4 w = W4[c], i = I4[c];
            s += w.x * i.x + w.y * i.y + w.z * i.z + w.w * i.w;
        }
    }
    Ut[idx] = f_to_bfu(s);
}

// ---------------- pack weights into MFMA B-fragment order (cg-major) ----------------
// Bp[l][cg][j][kc][lane][8], cg = 32-channel group (0..3),
// j = s*6 + g*2 + t: s 0=Ut 1=whh, g = gate (r,z,n), t = 16-ch tile within group.
// lane covers col = (cg*2+t)*16 + (lane&15), k = kc*32 + (lane>>4)*8.
__global__ void pack_b_k(const unsigned short* __restrict__ Ut,
                         const void* __restrict__ whh,
                         unsigned short* __restrict__ Bp,
                         const int* __restrict__ flags) {
    int idx = blockIdx.x * 256 + threadIdx.x;  // 3*4*12*4*64 total
    if (idx >= 3 * 4 * 12 * 4 * 64) return;
    int lane = idx & 63;
    int kc = (idx >> 6) & 3;
    int rest = idx >> 8;           // l*48 + cg*12 + j
    int j = rest % 12;
    int cg = (rest / 12) & 3;
    int l = rest / 48;
    int s = j / 6;
    int g = (j % 6) >> 1;
    int t = j & 1;
    int col = (cg * 2 + t) * 16 + (lane & 15);   // 0..127
    int k = kc * 32 + (lane >> 4) * 8;
    int row384 = g * 128 + col;
    unsigned short tmp[8];
    const unsigned short* src;
    if (s == 0) {
        src = Ut + (size_t)l * 49152 + row384 * 128 + k;
    } else if (flags[0]) {
        src = (const unsigned short*)whh + (size_t)row384 * 128 + k;
    } else {
        const float* wf = (const float*)whh + (size_t)row384 * 128 + k;
        for (int i = 0; i < 8; i++) tmp[i] = f_to_bfu(wf[i]);
        src = tmp;
    }
    unsigned short* dst = Bp + (size_t)l * 98304 + (((size_t)(cg * 12 + j) * 4 + kc) * 64 + lane) * 8;
    for (int i = 0; i < 8; i++) dst[i] = src[i];
}

// ---------------- aggregation: y[n,:] = sum_{e: dst=n} w_e * xb[src_e,:] ----------------
// XCD-aligned chunk remap (r8): chunk c runs on XCD (c/8)%8 so y rows are
// written on the XCD where gru reads them.

__global__ __launch_bounds__(256) void agg_k(const unsigned short* __restrict__ xb,
                                             const int* __restrict__ offs,
                                             const uint2* __restrict__ rec,
                                             unsigned short* __restrict__ y, int N,
                                             int nch) {
    int bid = blockIdx.x;
    int c = ((bid & 7) << 3) + ((bid >> 3) & 7) + ((bid >> 6) << 6);
    if (c >= nch) return;
    int node = c * 16 + (threadIdx.x >> 4);
    int l16 = threadIdx.x & 15;
    if (node >= N) return;
    int b = offs[node];
    int e2 = offs[node + 1];
    const uint4* xp4 = (const uint4*)xb;  // row = 16 uint4
    float a0[8], a1[8];
#pragma unroll
    for (int i = 0; i < 8; i++) { a0[i] = 0.f; a1[i] = 0.f; }

    auto fma_row = [&](float* acc, uint4 v, float w) {
        acc[0] += w * __builtin_bit_cast(float, v.x << 16);
        acc[1] += w * __builtin_bit_cast(float, v.x & 0xffff0000u);
        acc[2] += w * __builtin_bit_cast(float, v.y << 16);
        acc[3] += w * __builtin_bit_cast(float, v.y & 0xffff0000u);
        acc[4] += w * __builtin_bit_cast(float, v.z << 16);
        acc[5] += w * __builtin_bit_cast(float, v.z & 0xffff0000u);
        acc[6] += w * __builtin_bit_cast(float, v.w << 16);
        acc[7] += w * __builtin_bit_cast(float, v.w & 0xffff0000u);
    };

    int e = b;
    for (; e + 4 <= e2; e += 4) {
        uint2 r0 = rec[e], r1 = rec[e + 1], r2 = rec[e + 2], r3 = rec[e + 3];
        uint4 v0 = xp4[(size_t)r0.x * 16 + l16];
        uint4 v1 = xp4[(size_t)r1.x * 16 + l16];
        uint4 v2 = xp4[(size_t)r2.x * 16 + l16];
        uint4 v3 = xp4[(size_t)r3.x * 16 + l16];
        fma_row(a0, v0, __builtin_bit_cast(float, r0.y));
        fma_row(a1, v1, __builtin_bit_cast(float, r1.y));
        fma_row(a0, v2, __builtin_bit_cast(float, r2.y));
        fma_row(a1, v3, __builtin_bit_cast(float, r3.y));
    }
    for (; e < e2; e++) {
        uint2 r = rec[e];
        uint4 v = xp4[(size_t)r.x * 16 + l16];
        fma_row(a0, v, __builtin_bit_cast(float, r.y));
    }

    uint4 o;
    o.x = (unsigned int)f_to_bfu(a0[0] + a1[0]) | ((unsigned int)f_to_bfu(a0[1] + a1[1]) << 16);
    o.y = (unsigned int)f_to_bfu(a0[2] + a1[2]) | ((unsigned int)f_to_bfu(a0[3] + a1[3]) << 16);
    o.z = (unsigned int)f_to_bfu(a0[4] + a1[4]) | ((unsigned int)f_to_bfu(a0[5] + a1[5]) << 16);
    o.w = (unsigned int)f_to_bfu(a0[6] + a1[6]) | ((unsigned int)f_to_bfu(a0[7] + a1[7]) << 16);
    ((uint4*)y)[(size_t)node * 16 + l16] = o;
}

// ---------------- fused GRU (v8 structure + direct dtype output on last layer) ----------------
// v11 = revert to v8 (fusion refuted by r10 counters: 4-pass partial-line
// writes amplified WRITE 25->220MB, xin re-read x4, gather starved at 16
// waves/CU — split kernels with dispatch-order locality already overlap).
// New: last layer writes dtype-converted output directly to d_out (uniform
// in-kernel flags branch) — out_k and its 51MB xb roundtrip eliminated.

__global__ __launch_bounds__(512, 4) void gru_k(const unsigned short* __restrict__ y,
                                                const unsigned short* __restrict__ xin,
                                                void* __restrict__ xout,
                                                const unsigned short* __restrict__ Bp,
                                                const float* __restrict__ bih,
                                                const float* __restrict__ bhh, int N,
                                                const int* __restrict__ flags, int last) {
    __shared__ uint4 Blds[3072];  // 48KB: [12][4][64] x 16B

    int bid = blockIdx.x;
    int r8 = bid & 7;
    int inner = bid >> 3;
    int cg = inner & 3;
    int rb = ((inner >> 2) << 3) + r8;
    int row0 = rb << 7;  // *128
    if (row0 >= N) return;

    int tid = threadIdx.x;
    {
        const uint4* bsrc = (const uint4*)(Bp + (size_t)cg * 24576);
#pragma unroll
        for (int i = 0; i < 6; i++) Blds[tid + i * 512] = bsrc[tid + i * 512];
    }
    __syncthreads();

    int wave = tid >> 6;
    int wc = wave & 1;       // 16-ch tile within the 32-ch group
    int wr = wave >> 1;      // 0..3: 32-row slice
    int lane = tid & 63;
    int quad = lane >> 4;
    int m16 = lane & 15;
    const unsigned short* bl = (const unsigned short*)Blds;

    int rA[2];
#pragma unroll
    for (int rt = 0; rt < 2; rt++) {
        int r = row0 + wr * 32 + rt * 16 + m16;
        rA[rt] = (r < N) ? r : N - 1;
    }

    // acc[rt][s]: s=0 -> r (fused gi+gh), s=1 -> z (fused), s=2 -> gi_n, s=3 -> gh_n
    floatx4 acc[2][4];
#pragma unroll
    for (int rt = 0; rt < 2; rt++)
#pragma unroll
        for (int s = 0; s < 4; s++) acc[rt][s] = (floatx4){0.f, 0.f, 0.f, 0.f};

    bf16x8 aY[2][4], aX[2][4];

    // ---- Y loads: 8 issued, pinned above the MFMA cluster ----
#pragma unroll
    for (int rt = 0; rt < 2; rt++)
#pragma unroll
        for (int kc = 0; kc < 4; kc++)
            aY[rt][kc] = *(const bf16x8*)(y + (size_t)rA[rt] * 128 + kc * 32 + quad * 8);
    __builtin_amdgcn_sched_barrier(0);

    // ---- Y MFMAs (+ X loads free to hoist into this region) ----
#pragma unroll
    for (int rt = 0; rt < 2; rt++)
#pragma unroll
        for (int kc = 0; kc < 4; kc++)
            aX[rt][kc] = *(const bf16x8*)(xin + (size_t)rA[rt] * 128 + kc * 32 + quad * 8);

#pragma unroll
    for (int kc = 0; kc < 4; kc++) {
#pragma unroll
        for (int g = 0; g < 3; g++) {
            int jU = g * 2 + wc;
            bf16x8 b = *(const bf16x8*)(bl + ((size_t)(jU * 4 + kc) * 64 + lane) * 8);
            int s = (g == 2) ? 2 : g;
            acc[0][s] = __builtin_amdgcn_mfma_f32_16x16x32_bf16(aY[0][kc], b, acc[0][s], 0, 0, 0);
            acc[1][s] = __builtin_amdgcn_mfma_f32_16x16x32_bf16(aY[1][kc], b, acc[1][s], 0, 0, 0);
        }
    }
    __builtin_amdgcn_sched_barrier(0);

    // ---- X MFMAs ----
#pragma unroll
    for (int kc = 0; kc < 4; kc++) {
#pragma unroll
        for (int g = 0; g < 3; g++) {
            int jW = 6 + g * 2 + wc;
            bf16x8 b = *(const bf16x8*)(bl + ((size_t)(jW * 4 + kc) * 64 + lane) * 8);
            int s = (g == 2) ? 3 : g;
            acc[0][s] = __builtin_amdgcn_mfma_f32_16x16x32_bf16(aX[0][kc], b, acc[0][s], 0, 0, 0);
            acc[1][s] = __builtin_amdgcn_mfma_f32_16x16x32_bf16(aX[1][kc], b, acc[1][s], 0, 0, 0);
        }
    }

    // ---- epilogue ----
    int ch = cg * 32 + wc * 16 + m16;  // 0..127
    float b_r = bih[ch] + bhh[ch];
    float b_z = bih[128 + ch] + bhh[128 + ch];
    float bi_n = bih[256 + ch];
    float bh_n = bhh[256 + ch];
    int isb = last ? flags[0] : 1;  // intermediate layers always bf16
#pragma unroll
    for (int rt = 0; rt < 2; rt++) {
#pragma unroll
        for (int ri = 0; ri < 4; ri++) {
            int row = row0 + wr * 32 + rt * 16 + quad * 4 + ri;
            if (row >= N) continue;
            float sr = acc[rt][0][ri] + b_r;
            float sz = acc[rt][1][ri] + b_z;
            float gn = acc[rt][2][ri] + bi_n;
            float hn = acc[rt][3][ri] + bh_n;
            float r = __builtin_amdgcn_rcpf(1.f + __expf(-sr));
            float zg = __builtin_amdgcn_rcpf(1.f + __expf(-sz));
            float x2 = gn + r * hn;
            float n = 1.f - 2.f * __builtin_amdgcn_rcpf(1.f + __expf(2.f * x2));
            float h = bfu_to_f(xin[(size_t)row * 128 + ch]);
            float o = n + zg * (h - n);
            if (isb) ((unsigned short*)xout)[(size_t)row * 128 + ch] = f_to_bfu(o);
            else ((float*)xout)[(size_t)row * 128 + ch] = o;
        }
    }
}

// ---------------- launch ----------------

extern "C" void kernel_launch(void* const* d_in, const int* in_sizes, int n_in,
                              void* d_out, int out_size, void* d_ws, size_t ws_size,
                              hipStream_t stream) {
    const int N = in_sizes[0] / 128;
    const int E = in_sizes[1];
    const int NB = (N + NPB - 1) >> NPB_SHIFT;

    const void* z = d_in[0];
    const void* ew = d_in[1];
    const void* weight = d_in[2];
    const void* wih = d_in[3];
    const void* whh = d_in[4];
    const void* bih = d_in[5];
    const void* bhh = d_in[6];
    const unsigned int* eiu = (const unsigned int*)d_in[7];

    // y for layers 0,1 aliases d_out (dead before the last layer's write).
    // Layer 2: y lives in xb2 (its old role as xout is gone — last gru writes
    // d_out directly), so the final f32/bf16 output write never races y reads.
    unsigned short* y01 = (unsigned short*)d_out;

    size_t off = 0;
    char* base = (char*)d_ws;
    auto carve = [&](size_t bytes) -> void* {
        void* p = base + off;
        off = (off + bytes + 255) & ~(size_t)255;
        return p;
    };
    unsigned short* xb = (unsigned short*)carve((size_t)N * 128 * 2);
    unsigned short* xb2 = (unsigned short*)carve((size_t)N * 128 * 2);
    uint2* rec8 = (uint2*)carve((size_t)E * 8);   // binned merged records
    uint2* rec = (uint2*)carve((size_t)E * 8);    // final CSR records
    int* offsets = (int*)carve((size_t)(N + 1) * 4);
    int* bucketCnt = (int*)carve(MAXNB * 4);
    int* bucketBase = (int*)carve((MAXNB + 1) * 4);
    int* bucketCursor = (int*)carve(MAXNB * 4);
    unsigned short* Ut = (unsigned short*)carve((size_t)3 * 384 * 128 * 2);
    unsigned short* Bp = (unsigned short*)carve((size_t)3 * 48 * 4 * 64 * 8 * 2);
    float* bih_f = (float*)carve(384 * 4);
    float* bhh_f = (float*)carve(384 * 4);
    int* flags = (int*)carve(256);

    detect_k<<<1, 64, 0, stream>>>((const unsigned short*)bih, eiu, flags);

    cvt_bf16_k<<<(N * 128 + 255) / 256, 256, 0, stream>>>(z, xb, N * 128, flags);
    cvt_bias_k<<<3, 256, 0, stream>>>(bih, bhh, bih_f, bhh_f, flags);

    // hierarchical CSR build
    hipMemsetAsync(bucketCnt, 0, MAXNB * 4, stream);
    int gbin = (E + TILE - 1) / TILE;
    count_k<<<gbin, 256, 0, stream>>>(eiu, bucketCnt, E, flags);
    scanB_k<<<1, MAXNB, 0, stream>>>(bucketCnt, bucketBase, bucketCursor, NB, E);
    bin_k<<<gbin, 256, 0, stream>>>(eiu, ew, bucketCursor, rec8, E, flags);
    csr_k<<<NB, NPB, 0, stream>>>(rec8, bucketBase, offsets, rec, N, E);

    make_ut_k<<<(3 * 384 * 128 + 255) / 256, 256, 0, stream>>>(weight, wih, Ut, flags);
    pack_b_k<<<(3 * 4 * 12 * 4 * 64 + 255) / 256, 256, 0, stream>>>(Ut, whh, Bp, flags);

    // gru grid: XCD-swizzled (rb,cg); agg grid: XCD-aligned chunk remap.
    const int RB = (N + 127) >> 7;
    const int grid_gru = 8 * ((RB + 7) >> 3) * 4;
    const int nch = (N + 15) >> 4;
    const int grid_agg = ((nch + 63) >> 6) << 6;

    // layer 0: xb -> xb2
    agg_k<<<grid_agg, 256, 0, stream>>>(xb, offsets, rec, y01, N, nch);
    gru_k<<<grid_gru, 512, 0, stream>>>(y01, xb, xb2, Bp, bih_f, bhh_f, N, flags, 0);
    // layer 1: xb2 -> xb
    agg_k<<<grid_agg, 256, 0, stream>>>(xb2, offsets, rec, y01, N, nch);
    gru_k<<<grid_gru, 512, 0, stream>>>(y01, xb2, xb, Bp + 98304, bih_f, bhh_f, N, flags, 0);
    // layer 2: xb -> d_out (dtype-converted in-kernel); y in xb2 (free)
    agg_k<<<grid_agg, 256, 0, stream>>>(xb, offsets, rec, xb2, N, nch);
    gru_k<<<grid_gru, 512, 0, stream>>>(xb2, xb, d_out, Bp + 2 * 98304, bih_f, bhh_f, N, flags, 1);
}

// Round 12
// 577.802 us; speedup vs baseline: 1.3258x; 1.0187x over previous
//
#include <hip/hip_runtime.h>

typedef __bf16 bf16x8 __attribute__((ext_vector_type(8)));
typedef float floatx4 __attribute__((ext_vector_type(4)));

#define NPB 256        // nodes per bucket (power of 2)
#define NPB_SHIFT 8
#define MAXNB 1024     // max buckets supported (N <= 262144)
#define TILE 4096      // edges per binning block

static __device__ __forceinline__ float bfu_to_f(unsigned short u) {
    unsigned int x = ((unsigned int)u) << 16;
    return __builtin_bit_cast(float, x);
}
static __device__ __forceinline__ unsigned short f_to_bfu(float f) {
    unsigned int u = __builtin_bit_cast(unsigned int, f);
    unsigned int r = (u + 0x7fffu + ((u >> 16) & 1u)) >> 16;
    return (unsigned short)r;
}

// ---------------- dtype detection (parallel) ----------------
__global__ void detect_k(const unsigned short* __restrict__ bih_u,
                         const unsigned int* __restrict__ ei_u,
                         int* __restrict__ flags) {
    __shared__ int sv, sz;
    int t = threadIdx.x;  // 64
    if (t == 0) { sv = 0; sz = 0; }
    __syncthreads();
    unsigned short u = bih_u[2 * t];
    unsigned int ex = (u >> 7) & 0xFF;
    if (ex >= 64 && ex < 124) atomicAdd(&sv, 1);
    if (ei_u[2 * t + 1] == 0u) atomicAdd(&sz, 1);
    __syncthreads();
    if (t == 0) {
        flags[0] = (sv >= 48) ? 1 : 0;
        flags[1] = (sz == 64) ? 1 : 0;
    }
}

// ---------------- canonicalization ----------------

__global__ void cvt_bf16_k(const void* __restrict__ in, unsigned short* __restrict__ out,
                           int n, const int* __restrict__ flags) {
    int i = blockIdx.x * 256 + threadIdx.x;
    if (i >= n) return;
    if (flags[0]) out[i] = ((const unsigned short*)in)[i];
    else out[i] = f_to_bfu(((const float*)in)[i]);
}

__global__ void cvt_bias_k(const void* __restrict__ bih, const void* __restrict__ bhh,
                           float* __restrict__ bih_f, float* __restrict__ bhh_f,
                           const int* __restrict__ flags) {
    int i = blockIdx.x * 256 + threadIdx.x;
    if (i >= 768) return;
    const void* src = (i < 384) ? bih : bhh;
    int j = (i < 384) ? i : i - 384;
    float v = flags[0] ? bfu_to_f(((const unsigned short*)src)[j]) : ((const float*)src)[j];
    if (i < 384) bih_f[j] = v;
    else bhh_f[j] = v;
}

// ---------------- hierarchical CSR build ----------------

static __device__ __forceinline__ int load_idx(const unsigned int* eiu, size_t pos, int is64) {
    return (int)eiu[is64 ? 2 * pos : pos];
}

__global__ __launch_bounds__(256) void count_k(const unsigned int* __restrict__ eiu,
                                               int* __restrict__ bucketCnt, int E,
                                               const int* __restrict__ flags) {
    __shared__ int cnt[MAXNB];
    int t = threadIdx.x;
    for (int b = t; b < MAXNB; b += 256) cnt[b] = 0;
    __syncthreads();
    int is64 = flags[1];
    int e0 = blockIdx.x * TILE;
    int e1 = min(e0 + TILE, E);
    for (int e = e0 + t; e < e1; e += 256) {
        int d = load_idx(eiu, (size_t)E + e, is64);
        atomicAdd(&cnt[d >> NPB_SHIFT], 1);
    }
    __syncthreads();
    for (int b = t; b < MAXNB; b += 256) {
        int c = cnt[b];
        if (c) atomicAdd(&bucketCnt[b], c);
    }
}

__global__ void scanB_k(const int* __restrict__ bucketCnt, int* __restrict__ bucketBase,
                        int* __restrict__ bucketCursor, int NB, int E) {
    __shared__ int sh[MAXNB];
    int t = threadIdx.x;  // 1024 threads
    int v = (t < NB) ? bucketCnt[t] : 0;
    sh[t] = v;
    __syncthreads();
    for (int off = 1; off < MAXNB; off <<= 1) {
        int u = (t >= off) ? sh[t - off] : 0;
        __syncthreads();
        sh[t] += u;
        __syncthreads();
    }
    if (t < NB) {
        int b = sh[t] - v;
        bucketBase[t] = b;
        bucketCursor[t] = b;
    }
    if (t == 0) bucketBase[NB] = E;
}

// merged 8B record {s | dloc<<20, w}; s < 2^20, dloc = d&255 (r8 win).
__global__ __launch_bounds__(256) void bin_k(const unsigned int* __restrict__ eiu,
                                             const void* __restrict__ ew,
                                             int* __restrict__ bucketCursor,
                                             uint2* __restrict__ rec8, int E,
                                             const int* __restrict__ flags) {
    __shared__ int cnt[MAXNB];
    __shared__ int basel[MAXNB];
    int t = threadIdx.x;
    for (int b = t; b < MAXNB; b += 256) cnt[b] = 0;
    __syncthreads();
    int is64 = flags[1];
    int isb = flags[0];
    int e0 = blockIdx.x * TILE;
    int e1 = min(e0 + TILE, E);
    for (int e = e0 + t; e < e1; e += 256) {
        int d = load_idx(eiu, (size_t)E + e, is64);
        atomicAdd(&cnt[d >> NPB_SHIFT], 1);
    }
    __syncthreads();
    for (int b = t; b < MAXNB; b += 256) {
        int c = cnt[b];
        basel[b] = c ? atomicAdd(&bucketCursor[b], c) : 0;
        cnt[b] = 0;
    }
    __syncthreads();
    for (int e = e0 + t; e < e1; e += 256) {
        int s = load_idx(eiu, (size_t)e, is64);
        int d = load_idx(eiu, (size_t)E + e, is64);
        float w = isb ? bfu_to_f(((const unsigned short*)ew)[e]) : ((const float*)ew)[e];
        int b = d >> NPB_SHIFT;
        int p = basel[b] + atomicAdd(&cnt[b], 1);
        rec8[p] = make_uint2((unsigned int)s | ((unsigned int)(d & 255) << 20),
                             __builtin_bit_cast(unsigned int, w));
    }
}

__global__ __launch_bounds__(256) void csr_k(const uint2* __restrict__ rec8,
                                             const int* __restrict__ bucketBase,
                                             int* __restrict__ offsets,
                                             uint2* __restrict__ rec, int N, int E) {
    __shared__ int cnt[NPB];
    __shared__ int sh[NPB];
    __shared__ int cur[NPB];
    int t = threadIdx.x;
    int b = blockIdx.x;
    int n0 = b << NPB_SHIFT;
    int nodes = min(NPB, N - n0);
    int ebase = bucketBase[b];
    int ecnt = bucketBase[b + 1] - ebase;

    cnt[t] = 0;
    __syncthreads();
    for (int i = t; i < ecnt; i += 256) {
        int d = (rec8[ebase + i].x >> 20) & 255;
        atomicAdd(&cnt[d], 1);
    }
    __syncthreads();
    int v = cnt[t];
    sh[t] = v;
    __syncthreads();
    for (int off = 1; off < NPB; off <<= 1) {
        int u = (t >= off) ? sh[t - off] : 0;
        __syncthreads();
        sh[t] += u;
        __syncthreads();
    }
    int loff = sh[t] - v;  // exclusive
    if (t < nodes) offsets[n0 + t] = ebase + loff;
    cur[t] = ebase + loff;
    if (b == 0 && t == 0) offsets[N] = E;
    __syncthreads();
    for (int i = t; i < ecnt; i += 256) {
        uint2 r = rec8[ebase + i];
        int d = (r.x >> 20) & 255;
        int p = atomicAdd(&cur[d], 1);
        rec[p] = make_uint2(r.x & 0xFFFFFu, r.y);
    }
}

// ---------------- Ut_l[j][a] = sum_k W_l[a][k] * w_ih[j][k] ----------------

static __device__ __forceinline__ float dot8_bf(uint4 wv, uint4 iv) {
    float s;
    s  = bfu_to_f((unsigned short)(wv.x)) * bfu_to_f((unsigned short)(iv.x));
    s += bfu_to_f((unsigned short)(wv.x >> 16)) * bfu_to_f((unsigned short)(iv.x >> 16));
    s += bfu_to_f((unsigned short)(wv.y)) * bfu_to_f((unsigned short)(iv.y));
    s += bfu_to_f((unsigned short)(wv.y >> 16)) * bfu_to_f((unsigned short)(iv.y >> 16));
    s += bfu_to_f((unsigned short)(wv.z)) * bfu_to_f((unsigned short)(iv.z));
    s += bfu_to_f((unsigned short)(wv.z >> 16)) * bfu_to_f((unsigned short)(iv.z >> 16));
    s += bfu_to_f((unsigned short)(wv.w)) * bfu_to_f((unsigned short)(iv.w));
    s += bfu_to_f((unsigned short)(wv.w >> 16)) * bfu_to_f((unsigned short)(iv.w >> 16));
    return s;
}

__global__ void make_ut_k(const void* __restrict__ weight, const void* __restrict__ wih,
                          unsigned short* __restrict__ Ut, const int* __restrict__ flags) {
    int idx = blockIdx.x * 256 + threadIdx.x;  // l*49152 + j*128 + a
    if (idx >= 3 * 384 * 128) return;
    int isb = flags[0];
    int a = idx & 127;
    int j = (idx >> 7) % 384;
    int l = idx / (384 * 128);
    float s = 0.f;
    if (isb) {
        const uint4* W4 = (const uint4*)((const unsigned short*)weight + (size_t)l * 16384 + a * 128);
        const uint4* I4 = (const uint4*)((const unsigned short*)wih + (size_t)j * 128);
#pragma unroll
        for (int c = 0; c < 16; c++) s += dot8_bf(W4[c], I4[c]);
    } else {
        const float4* W4 = (const float4*)((const float*)weight + (size_t)l * 16384 + a * 128);
        const float4* I4 = (const float4*)((const float*)wih + (size_t)j * 128);
#pragma unroll
        for (int c = 0; c < 32; c++) {
            float4 w = W4[c], i = I4[c];
            s += w.x * i.x + w.y * i.y + w.z * i.z + w.w * i.w;
        }
    }
    Ut[idx] = f_to_bfu(s);
}

// ---------------- pack weights into MFMA B-fragment order (cg8-major) ----------------
// v12: Bp[l][cg8][j][kc][lane][8], cg8 = 16-channel group (0..7),
// j = s*3 + g: s 0=Ut 1=whh, g = gate (r,z,n). Slice per cg8 = 24KB.
// lane covers col = cg8*16 + (lane&15), k = kc*32 + (lane>>4)*8.
__global__ void pack_b_k(const unsigned short* __restrict__ Ut,
                         const void* __restrict__ whh,
                         unsigned short* __restrict__ Bp,
                         const int* __restrict__ flags) {
    int idx = blockIdx.x * 256 + threadIdx.x;  // 3*8*6*4*64 = 36864 total
    if (idx >= 3 * 8 * 6 * 4 * 64) return;
    int lane = idx & 63;
    int kc = (idx >> 6) & 3;
    int rest = idx >> 8;           // l*48 + cg8*6 + j
    int j = rest % 6;
    int cg8 = (rest / 6) & 7;
    int l = rest / 48;
    int s = j / 3;
    int g = j % 3;
    int col = cg8 * 16 + (lane & 15);   // 0..127
    int k = kc * 32 + (lane >> 4) * 8;
    int row384 = g * 128 + col;
    unsigned short tmp[8];
    const unsigned short* src;
    if (s == 0) {
        src = Ut + (size_t)l * 49152 + row384 * 128 + k;
    } else if (flags[0]) {
        src = (const unsigned short*)whh + (size_t)row384 * 128 + k;
    } else {
        const float* wf = (const float*)whh + (size_t)row384 * 128 + k;
        for (int i = 0; i < 8; i++) tmp[i] = f_to_bfu(wf[i]);
        src = tmp;
    }
    unsigned short* dst = Bp + (size_t)l * 98304 + (((size_t)(cg8 * 6 + j) * 4 + kc) * 64 + lane) * 8;
    for (int i = 0; i < 8; i++) dst[i] = src[i];
}

// ---------------- aggregation: y[n,:] = sum_{e: dst=n} w_e * xb[src_e,:] ----------------
// XCD-aligned chunk remap (r8): chunk c runs on XCD (c/8)%8 so y rows are
// written on the XCD where gru reads them.

__global__ __launch_bounds__(256) void agg_k(const unsigned short* __restrict__ xb,
                                             const int* __restrict__ offs,
                                             const uint2* __restrict__ rec,
                                             unsigned short* __restrict__ y, int N,
                                             int nch) {
    int bid = blockIdx.x;
    int c = ((bid & 7) << 3) + ((bid >> 3) & 7) + ((bid >> 6) << 6);
    if (c >= nch) return;
    int node = c * 16 + (threadIdx.x >> 4);
    int l16 = threadIdx.x & 15;
    if (node >= N) return;
    int b = offs[node];
    int e2 = offs[node + 1];
    const uint4* xp4 = (const uint4*)xb;  // row = 16 uint4
    float a0[8], a1[8];
#pragma unroll
    for (int i = 0; i < 8; i++) { a0[i] = 0.f; a1[i] = 0.f; }

    auto fma_row = [&](float* acc, uint4 v, float w) {
        acc[0] += w * __builtin_bit_cast(float, v.x << 16);
        acc[1] += w * __builtin_bit_cast(float, v.x & 0xffff0000u);
        acc[2] += w * __builtin_bit_cast(float, v.y << 16);
        acc[3] += w * __builtin_bit_cast(float, v.y & 0xffff0000u);
        acc[4] += w * __builtin_bit_cast(float, v.z << 16);
        acc[5] += w * __builtin_bit_cast(float, v.z & 0xffff0000u);
        acc[6] += w * __builtin_bit_cast(float, v.w << 16);
        acc[7] += w * __builtin_bit_cast(float, v.w & 0xffff0000u);
    };

    int e = b;
    for (; e + 4 <= e2; e += 4) {
        uint2 r0 = rec[e], r1 = rec[e + 1], r2 = rec[e + 2], r3 = rec[e + 3];
        uint4 v0 = xp4[(size_t)r0.x * 16 + l16];
        uint4 v1 = xp4[(size_t)r1.x * 16 + l16];
        uint4 v2 = xp4[(size_t)r2.x * 16 + l16];
        uint4 v3 = xp4[(size_t)r3.x * 16 + l16];
        fma_row(a0, v0, __builtin_bit_cast(float, r0.y));
        fma_row(a1, v1, __builtin_bit_cast(float, r1.y));
        fma_row(a0, v2, __builtin_bit_cast(float, r2.y));
        fma_row(a1, v3, __builtin_bit_cast(float, r3.y));
    }
    for (; e < e2; e++) {
        uint2 r = rec[e];
        uint4 v = xp4[(size_t)r.x * 16 + l16];
        fma_row(a0, v, __builtin_bit_cast(float, r.y));
    }

    uint4 o;
    o.x = (unsigned int)f_to_bfu(a0[0] + a1[0]) | ((unsigned int)f_to_bfu(a0[1] + a1[1]) << 16);
    o.y = (unsigned int)f_to_bfu(a0[2] + a1[2]) | ((unsigned int)f_to_bfu(a0[3] + a1[3]) << 16);
    o.z = (unsigned int)f_to_bfu(a0[4] + a1[4]) | ((unsigned int)f_to_bfu(a0[5] + a1[5]) << 16);
    o.w = (unsigned int)f_to_bfu(a0[6] + a1[6]) | ((unsigned int)f_to_bfu(a0[7] + a1[7]) << 16);
    ((uint4*)y)[(size_t)node * 16 + l16] = o;
}

// ---------------- fused GRU (v12: cg split 4->8 ways for occupancy) ----------------
// r11 post-mortem: occupancy ladder is the only lever that has paid
// (19%->92.7us, 39%->81.6, 53%->68); per-wave ILP nulled 4x. cg8 halves the
// B-slice to 24KB -> LDS permits 6 blocks/CU; 32-wave HW cap -> 4 blocks x
// 8 waves = up to 100% occupancy (vs 52%). Per-wave: 1 row-tile (16 rows),
// acc[4] = 16 AGPR, 8 A-frags = 32 VGPR. Total stage traffic unchanged
// (6272 x 24KB = 3136 x 48KB). launch_bounds(512,6) caps 85 regs (floor for
// allocator); actual residency can still reach 4 blocks if regs <= 64.
// A-rows read by 8 dispatch-adjacent blocks -> same XCD, L2 absorbs (r8).

__global__ __launch_bounds__(512, 6) void gru_k(const unsigned short* __restrict__ y,
                                                const unsigned short* __restrict__ xin,
                                                void* __restrict__ xout,
                                                const unsigned short* __restrict__ Bp,
                                                const float* __restrict__ bih,
                                                const float* __restrict__ bhh, int N,
                                                const int* __restrict__ flags, int last) {
    __shared__ uint4 Blds[1536];  // 24KB: [6][4][64] x 16B (one cg8 slice)

    int bid = blockIdx.x;
    int r8 = bid & 7;
    int inner = bid >> 3;
    int cg8 = inner & 7;
    int rb = ((inner >> 3) << 3) + r8;
    int row0 = rb << 7;  // *128
    if (row0 >= N) return;

    int tid = threadIdx.x;
    {
        const uint4* bsrc = (const uint4*)(Bp + (size_t)cg8 * 12288);
#pragma unroll
        for (int i = 0; i < 3; i++) Blds[tid + i * 512] = bsrc[tid + i * 512];
    }
    __syncthreads();

    int wr = tid >> 6;       // 0..7: 16-row slice
    int lane = tid & 63;
    int quad = lane >> 4;
    int m16 = lane & 15;
    const unsigned short* bl = (const unsigned short*)Blds;

    int r = row0 + wr * 16 + m16;
    int rA = (r < N) ? r : N - 1;

    // acc[s]: s=0 -> r (fused gi+gh), s=1 -> z (fused), s=2 -> gi_n, s=3 -> gh_n
    floatx4 acc[4];
#pragma unroll
    for (int s = 0; s < 4; s++) acc[s] = (floatx4){0.f, 0.f, 0.f, 0.f};

    bf16x8 aY[4], aX[4];

    // ---- Y loads: 4 issued, pinned above the MFMA cluster ----
#pragma unroll
    for (int kc = 0; kc < 4; kc++)
        aY[kc] = *(const bf16x8*)(y + (size_t)rA * 128 + kc * 32 + quad * 8);
    __builtin_amdgcn_sched_barrier(0);

    // ---- X loads + Y MFMAs ----
#pragma unroll
    for (int kc = 0; kc < 4; kc++)
        aX[kc] = *(const bf16x8*)(xin + (size_t)rA * 128 + kc * 32 + quad * 8);

#pragma unroll
    for (int kc = 0; kc < 4; kc++) {
#pragma unroll
        for (int g = 0; g < 3; g++) {
            bf16x8 b = *(const bf16x8*)(bl + ((size_t)(g * 4 + kc) * 64 + lane) * 8);
            int s = (g == 2) ? 2 : g;
            acc[s] = __builtin_amdgcn_mfma_f32_16x16x32_bf16(aY[kc], b, acc[s], 0, 0, 0);
        }
    }
    __builtin_amdgcn_sched_barrier(0);

    // ---- X MFMAs ----
#pragma unroll
    for (int kc = 0; kc < 4; kc++) {
#pragma unroll
        for (int g = 0; g < 3; g++) {
            bf16x8 b = *(const bf16x8*)(bl + ((size_t)((3 + g) * 4 + kc) * 64 + lane) * 8);
            int s = (g == 2) ? 3 : g;
            acc[s] = __builtin_amdgcn_mfma_f32_16x16x32_bf16(aX[kc], b, acc[s], 0, 0, 0);
        }
    }

    // ---- epilogue ----
    int ch = cg8 * 16 + m16;  // 0..127
    float b_r = bih[ch] + bhh[ch];
    float b_z = bih[128 + ch] + bhh[128 + ch];
    float bi_n = bih[256 + ch];
    float bh_n = bhh[256 + ch];
    int isb = last ? flags[0] : 1;  // intermediate layers always bf16
#pragma unroll
    for (int ri = 0; ri < 4; ri++) {
        int row = row0 + wr * 16 + quad * 4 + ri;
        if (row >= N) continue;
        float sr = acc[0][ri] + b_r;
        float sz = acc[1][ri] + b_z;
        float gn = acc[2][ri] + bi_n;
        float hn = acc[3][ri] + bh_n;
        float rg = __builtin_amdgcn_rcpf(1.f + __expf(-sr));
        float zg = __builtin_amdgcn_rcpf(1.f + __expf(-sz));
        float x2 = gn + rg * hn;
        float n = 1.f - 2.f * __builtin_amdgcn_rcpf(1.f + __expf(2.f * x2));
        float h = bfu_to_f(xin[(size_t)row * 128 + ch]);
        float o = n + zg * (h - n);
        if (isb) ((unsigned short*)xout)[(size_t)row * 128 + ch] = f_to_bfu(o);
        else ((float*)xout)[(size_t)row * 128 + ch] = o;
    }
}

// ---------------- launch ----------------

extern "C" void kernel_launch(void* const* d_in, const int* in_sizes, int n_in,
                              void* d_out, int out_size, void* d_ws, size_t ws_size,
                              hipStream_t stream) {
    const int N = in_sizes[0] / 128;
    const int E = in_sizes[1];
    const int NB = (N + NPB - 1) >> NPB_SHIFT;

    const void* z = d_in[0];
    const void* ew = d_in[1];
    const void* weight = d_in[2];
    const void* wih = d_in[3];
    const void* whh = d_in[4];
    const void* bih = d_in[5];
    const void* bhh = d_in[6];
    const unsigned int* eiu = (const unsigned int*)d_in[7];

    // y for layers 0,1 aliases d_out (dead before the last layer's write).
    // Layer 2's y lives in xb2; last gru writes d_out directly.
    unsigned short* y01 = (unsigned short*)d_out;

    size_t off = 0;
    char* base = (char*)d_ws;
    auto carve = [&](size_t bytes) -> void* {
        void* p = base + off;
        off = (off + bytes + 255) & ~(size_t)255;
        return p;
    };
    unsigned short* xb = (unsigned short*)carve((size_t)N * 128 * 2);
    unsigned short* xb2 = (unsigned short*)carve((size_t)N * 128 * 2);
    uint2* rec8 = (uint2*)carve((size_t)E * 8);   // binned merged records
    uint2* rec = (uint2*)carve((size_t)E * 8);    // final CSR records
    int* offsets = (int*)carve((size_t)(N + 1) * 4);
    int* bucketCnt = (int*)carve(MAXNB * 4);
    int* bucketBase = (int*)carve((MAXNB + 1) * 4);
    int* bucketCursor = (int*)carve(MAXNB * 4);
    unsigned short* Ut = (unsigned short*)carve((size_t)3 * 384 * 128 * 2);
    unsigned short* Bp = (unsigned short*)carve((size_t)3 * 8 * 6 * 4 * 64 * 8 * 2);
    float* bih_f = (float*)carve(384 * 4);
    float* bhh_f = (float*)carve(384 * 4);
    int* flags = (int*)carve(256);

    detect_k<<<1, 64, 0, stream>>>((const unsigned short*)bih, eiu, flags);

    cvt_bf16_k<<<(N * 128 + 255) / 256, 256, 0, stream>>>(z, xb, N * 128, flags);
    cvt_bias_k<<<3, 256, 0, stream>>>(bih, bhh, bih_f, bhh_f, flags);

    // hierarchical CSR build
    hipMemsetAsync(bucketCnt, 0, MAXNB * 4, stream);
    int gbin = (E + TILE - 1) / TILE;
    count_k<<<gbin, 256, 0, stream>>>(eiu, bucketCnt, E, flags);
    scanB_k<<<1, MAXNB, 0, stream>>>(bucketCnt, bucketBase, bucketCursor, NB, E);
    bin_k<<<gbin, 256, 0, stream>>>(eiu, ew, bucketCursor, rec8, E, flags);
    csr_k<<<NB, NPB, 0, stream>>>(rec8, bucketBase, offsets, rec, N, E);

    make_ut_k<<<(3 * 384 * 128 + 255) / 256, 256, 0, stream>>>(weight, wih, Ut, flags);
    pack_b_k<<<(3 * 8 * 6 * 4 * 64 + 255) / 256, 256, 0, stream>>>(Ut, whh, Bp, flags);

    // gru grid: XCD-swizzled (rb, cg8); agg grid: XCD-aligned chunk remap.
    const int RB = (N + 127) >> 7;
    const int grid_gru = 8 * ((RB + 7) >> 3) * 8;
    const int nch = (N + 15) >> 4;
    const int grid_agg = ((nch + 63) >> 6) << 6;

    // layer 0: xb -> xb2
    agg_k<<<grid_agg, 256, 0, stream>>>(xb, offsets, rec, y01, N, nch);
    gru_k<<<grid_gru, 512, 0, stream>>>(y01, xb, xb2, Bp, bih_f, bhh_f, N, flags, 0);
    // layer 1: xb2 -> xb
    agg_k<<<grid_agg, 256, 0, stream>>>(xb2, offsets, rec, y01, N, nch);
    gru_k<<<grid_gru, 512, 0, stream>>>(y01, xb2, xb, Bp + 98304, bih_f, bhh_f, N, flags, 0);
    // layer 2: xb -> d_out (dtype-converted in-kernel); y in xb2
    agg_k<<<grid_agg, 256, 0, stream>>>(xb, offsets, rec, xb2, N, nch);
    gru_k<<<grid_gru, 512, 0, stream>>>(xb2, xb, d_out, Bp + 2 * 98304, bih_f, bhh_f, N, flags, 1);
}